// Round 1
// baseline (104.400 us; speedup 1.0000x reference)
//
#include <hip/hip_runtime.h>

#define EPSF 1e-12f

#define B_SZ 256
#define DIN 512
#define DOUT 512
#define KN 16
#define NSEG 15

#define O_TILE 32
#define I_CHUNK 16
#define N_CHUNK (DIN / I_CHUNK)   // 32 i-chunks -> 32 partials
#define ROW_W 34                  // words per LDS table row: 16 (C,S) pairs + 2 pad
#define ROW_B (ROW_W * 4)         // 136 bytes

// ---------------------------------------------------------------------------
// Kernel 1: per-(b,i) Hermite weights + segment byte-offset.
// y(b,o,i) = w.x*C[k] + w.y*S[k] + w.z*C[k+1] + w.w*S[k+1]
// Extrapolation folds into the same form.
// Layout [i][b] so the main kernel (lanes span b) reads coalesced.
// ---------------------------------------------------------------------------
__global__ __launch_bounds__(256) void kan_weights(
    const float* __restrict__ x, const float* __restrict__ knots,
    float4* __restrict__ w4, int* __restrict__ koff) {
  int flat = blockIdx.x * 256 + threadIdx.x;    // 0..131071
  int b = flat & (B_SZ - 1);
  int i = flat >> 8;
  float x0 = knots[0];
  float xN = knots[KN - 1];
  float dx = (xN - x0) / (float)(KN - 1);
  float xv = x[b * DIN + i];
  float4 w;
  int k;
  if (xv < x0) {                 // left linear extrapolation
    w = make_float4(1.f, xv - x0, 0.f, 0.f); k = 0;
  } else if (xv > xN) {          // right linear extrapolation
    w = make_float4(0.f, 0.f, 1.f, xv - xN); k = NSEG - 1;
  } else {
    float u = (xv - x0) / (dx + EPSF);
    k = (int)floorf(u);
    if (k > NSEG - 1) k = NSEG - 1;
    float t = u - (float)k;
    float t2 = t * t, t3 = t2 * t;
    w = make_float4(2.f * t3 - 3.f * t2 + 1.f,
                    dx * (t3 - 2.f * t2 + t),
                    -2.f * t3 + 3.f * t2,
                    dx * (t3 - t2));
  }
  w4[i * B_SZ + b] = w;
  koff[i * B_SZ + b] = k * 8;    // byte offset of pair k within a table row
}

// ---------------------------------------------------------------------------
// Kernel 2: main. Grid 512 = 16 o-tiles x 32 i-chunks. 256 threads = all b.
// Phase A: build (C,S) table rows in LDS (fused PCHIP slopes; coeffs row
//          staged in registers, coalesced 1KB-chunk global reads).
// Phase B: lane=b; per (i,o): 2x ds_read_b64 gather (wave-uniform row base,
//          per-lane k -> distinct bank-pairs, broadcast on dups) + 4 FMA.
// ---------------------------------------------------------------------------
__global__ __launch_bounds__(256) void kan_main(
    const float* __restrict__ coeffs, const float* __restrict__ knots,
    const float4* __restrict__ w4, const int* __restrict__ koff,
    float* __restrict__ part) {
  __shared__ float tbl[O_TILE * I_CHUNK * ROW_W];   // 512 rows * 136 B = 68 KB
  int bid = blockIdx.x;
  int c  = bid >> 4;           // i-chunk 0..31
  int ot = bid & 15;           // o-tile  0..15
  int i0 = c * I_CHUNK;
  int o0 = ot * O_TILE;
  int t = threadIdx.x;

  // hoisted knot-derived constants (wave-uniform)
  float kn[KN];
#pragma unroll
  for (int j = 0; j < 4; ++j) {
    float4 kk = reinterpret_cast<const float4*>(knots)[j];
    kn[4 * j + 0] = kk.x; kn[4 * j + 1] = kk.y;
    kn[4 * j + 2] = kk.z; kn[4 * j + 3] = kk.w;
  }
  float h[NSEG];
#pragma unroll
  for (int j = 0; j < NSEG; ++j) h[j] = kn[j + 1] - kn[j];

  // ---- Phase A: 512 rows / 256 threads = 2 rows each ----
#pragma unroll
  for (int rep = 0; rep < 2; ++rep) {
    int r  = t + rep * 256;    // 0..511
    int il = r & 15;           // i within chunk (fast dim -> coalesced reads)
    int ol = r >> 4;           // o within tile
    // row index in tbl = ol*16 + il = r  (identity)
    const float* crow = coeffs + ((size_t)(o0 + ol) * DIN + (i0 + il)) * KN;
    float C[KN];
#pragma unroll
    for (int j = 0; j < 4; ++j) {
      float4 v = reinterpret_cast<const float4*>(crow)[j];
      C[4 * j + 0] = v.x; C[4 * j + 1] = v.y;
      C[4 * j + 2] = v.z; C[4 * j + 3] = v.w;
    }
    float del[NSEG];
#pragma unroll
    for (int j = 0; j < NSEG; ++j) del[j] = (C[j + 1] - C[j]) / (h[j] + EPSF);
    float d[KN];
    {
      float d0 = ((2.f * h[0] + h[1]) * del[0] - h[0] * del[1]) / (h[0] + h[1] + EPSF);
      if (d0 * del[0] <= 0.f) d0 = 0.f;
      else if (del[0] * del[1] < 0.f && fabsf(d0) > 3.f * fabsf(del[0])) d0 = 3.f * del[0];
      d[0] = d0;
      float dn = ((2.f * h[14] + h[13]) * del[14] - h[14] * del[13]) / (h[14] + h[13] + EPSF);
      if (dn * del[14] <= 0.f) dn = 0.f;
      else if (del[14] * del[13] < 0.f && fabsf(dn) > 3.f * fabsf(del[14])) dn = 3.f * del[14];
      d[15] = dn;
    }
#pragma unroll
    for (int j = 1; j <= 14; ++j) {
      float del0 = del[j - 1], del1 = del[j];
      float w1 = 2.f * h[j] + h[j - 1];
      float w2 = h[j] + 2.f * h[j - 1];
      float e0 = del0 + EPSF, e1 = del1 + EPSF;
      float prod = e0 * e1;
      // == (w1+w2)/(w1/e0 + w2/e1 + EPS), single division (diff ~ulps)
      float dj = (w1 + w2) * prod / (w1 * e1 + w2 * e0 + EPSF * prod);
      d[j] = (del0 * del1 > 0.f) ? dj : 0.f;
    }
    float2* rowp = reinterpret_cast<float2*>(&tbl[r * ROW_W]);
#pragma unroll
    for (int j = 0; j < KN; ++j) rowp[j] = make_float2(C[j], d[j]);
  }
  __syncthreads();

  // ---- Phase B: accumulate ----
  float acc[O_TILE];
#pragma unroll
  for (int o = 0; o < O_TILE; ++o) acc[o] = 0.f;
  int b = t;   // thread owns one sample row b = 0..255
  for (int il = 0; il < I_CHUNK; ++il) {
    float4 w = w4[(i0 + il) * B_SZ + b];          // coalesced
    int kb = koff[(i0 + il) * B_SZ + b];          // coalesced
    const char* base = reinterpret_cast<const char*>(tbl) + il * ROW_B + kb;
#pragma unroll
    for (int ol = 0; ol < O_TILE; ++ol) {
      // row (ol*16 + il): per-o stride = 16*136 = 2176 B (imm-friendly)
      float2 p0 = *reinterpret_cast<const float2*>(base + ol * (I_CHUNK * ROW_B));
      float2 p1 = *reinterpret_cast<const float2*>(base + ol * (I_CHUNK * ROW_B) + 8);
      acc[ol] = fmaf(w.x, p0.x,
                fmaf(w.y, p0.y,
                fmaf(w.z, p1.x,
                fmaf(w.w, p1.y, acc[ol]))));
    }
  }
  // partials [c][o][b] -> coalesced stores (lanes span b)
#pragma unroll
  for (int ol = 0; ol < O_TILE; ++ol)
    part[((size_t)c * DOUT + (o0 + ol)) * B_SZ + b] = acc[ol];
}

// ---------------------------------------------------------------------------
// Kernel 3: reduce 32 partials + bias. part reads coalesced (lanes span b);
// out is 512 KB -> partial-line writes merge in L2 before eviction.
// ---------------------------------------------------------------------------
__global__ __launch_bounds__(256) void kan_reduce(
    const float* __restrict__ part, const float* __restrict__ bias,
    float* __restrict__ out) {
  int flat = blockIdx.x * 256 + threadIdx.x;   // 0..131071
  int b = flat & (B_SZ - 1);
  int o = flat >> 8;
  float acc = bias[o];
#pragma unroll 4
  for (int c = 0; c < N_CHUNK; ++c)
    acc += part[((size_t)c * DOUT + o) * B_SZ + b];
  out[b * DOUT + o] = acc;
}

extern "C" void kernel_launch(void* const* d_in, const int* in_sizes, int n_in,
                              void* d_out, int out_size, void* d_ws, size_t ws_size,
                              hipStream_t stream) {
  const float* x      = (const float*)d_in[0];
  const float* knots  = (const float*)d_in[1];
  const float* coeffs = (const float*)d_in[2];
  const float* bias   = (const float*)d_in[3];
  float* out = (float*)d_out;

  char* ws = (char*)d_ws;
  float*  part = (float*)ws;                                   // 16 MB
  float4* w4   = (float4*)(ws + (size_t)16 * 1024 * 1024);     // 2 MB
  int*    koff = (int*)(ws + (size_t)18 * 1024 * 1024);        // 512 KB

  kan_weights<<<512, 256, 0, stream>>>(x, knots, w4, koff);
  kan_main   <<<512, 256, 0, stream>>>(coeffs, knots, w4, koff, part);
  kan_reduce <<<512, 256, 0, stream>>>(part, bias, out);
}